// Round 2
// baseline (303.403 us; speedup 1.0000x reference)
//
#include <hip/hip_runtime.h>
#include <hip/hip_bf16.h>
#include <math.h>

#define S_LEN 2048
#define DK 64
#define TQ 32          // queries per block
#define KLW 320        // klocal band width
#define NCH 5          // 5 chunks of 64 keys
#define PSTR 320       // Ps row stride (floats); banks via XOR swizzle; 32*320*4B = 40960B -> 4 blocks/CU

typedef __attribute__((ext_vector_type(8))) short bf16x8;
typedef __attribute__((ext_vector_type(4))) float f32x4;

__device__ __forceinline__ bf16x8 pack8(f32x4 a, f32x4 b) {
    union { __hip_bfloat162 h[4]; bf16x8 v; } u;
    u.h[0] = __float22bfloat162_rn(make_float2(a[0], a[1]));
    u.h[1] = __float22bfloat162_rn(make_float2(a[2], a[3]));
    u.h[2] = __float22bfloat162_rn(make_float2(b[0], b[1]));
    u.h[3] = __float22bfloat162_rn(make_float2(b[2], b[3]));
    return u.v;
}

// Swizzle: element kl of row q lives at Ps[q*PSTR + (kl ^ ((q&7)<<2))].
// XOR constant has only bits 2..4 -> 16B granules permute within each 32-float
// block; 4-aligned vector reads stay contiguous ((x^C)+i == (x+i)^C for i<4).

__global__ __launch_bounds__(256, 4) void band_attn_v9(
    const float* __restrict__ Q,
    const float* __restrict__ K,
    const float* __restrict__ V,
    float* __restrict__ ctx_out,   // [BH, S, DK]
    float* __restrict__ attn_out)  // [BH, S, S]
{
    __shared__ __align__(16) float Ps[TQ * PSTR];   // 40960 B -> 4 blocks/CU

    const int tid  = threadIdx.x;

    // XCD-aware swizzle (T1): dispatch round-robins physical blocks over 8 XCDs.
    // Map so each XCD owns 128 consecutive logical tiles (= 2 heads, K+V 2.1 MB
    // -> L2-resident band re-reads instead of L3).
    const int nb = gridDim.x;
    int lb = blockIdx.x;
    if ((nb & 7) == 0) {
        const int per = nb >> 3;
        lb = (blockIdx.x & 7) * per + (blockIdx.x >> 3);
    }
    const int bh   = lb >> 6;                    // 64 tiles per head
    const int q0   = (lb & 63) * TQ;
    const int base = q0 - 128;                   // kg = base + kl; base % 4 == 0

    const int lane = tid & 63;
    const int wv   = tid >> 6;
    const int col  = lane & 15;
    const int quad = lane >> 4;

    const float* Qh = Q + ((size_t)bh * S_LEN + q0) * DK;
    const float* Kh = K + (size_t)bh * S_LEN * DK;
    const float* Vh = V + (size_t)bh * S_LEN * DK;

    // ---- Q A-frags (pre-scaled by 1/8), loaded once ----
    bf16x8 qf[2][2];
    #pragma unroll
    for (int qt = 0; qt < 2; ++qt)
        #pragma unroll
        for (int h = 0; h < 2; ++h) {
            const float* qp = Qh + (size_t)(16 * qt + col) * DK + 32 * h + 8 * quad;
            f32x4 a = *(const f32x4*)qp;
            f32x4 b = *(const f32x4*)(qp + 4);
            a *= 0.125f; b *= 0.125f;
            qf[qt][h] = pack8(a, b);
        }

    // ---- score phase: B-frags straight from global K ----
    #pragma unroll
    for (int c = 0; c < NCH; ++c) {
        const int kl  = c * 64 + 16 * wv + col;          // this lane's key (klocal)
        const int kg  = base + kl;
        const int kgc = min(max(kg, 0), S_LEN - 1);      // clamp; mask fixes OOB
        bf16x8 kf[2];
        #pragma unroll
        for (int h = 0; h < 2; ++h) {
            const float* kp = Kh + (size_t)kgc * DK + 32 * h + 8 * quad;
            kf[h] = pack8(*(const f32x4*)kp, *(const f32x4*)(kp + 4));
        }
        #pragma unroll
        for (int qt = 0; qt < 2; ++qt) {
            f32x4 acc = {0.f, 0.f, 0.f, 0.f};
            acc = __builtin_amdgcn_mfma_f32_16x16x32_bf16(qf[qt][0], kf[0], acc, 0, 0, 0);
            acc = __builtin_amdgcn_mfma_f32_16x16x32_bf16(qf[qt][1], kf[1], acc, 0, 0, 0);
            #pragma unroll
            for (int r = 0; r < 4; ++r) {
                const int qloc = 16 * qt + quad * 4 + r;
                const bool ok = ((unsigned)kg < S_LEN) && (kl > qloc) && (kl <= qloc + 255);
                Ps[qloc * PSTR + (kl ^ ((qloc & 7) << 2))] = ok ? acc[r] : -INFINITY;
            }
        }
    }

    __syncthreads();   // barrier 1: K loads retired long ago -> cheap vmcnt

    // ---- softmax: LDS-only (NO global stores before barrier 2!) ----
    #pragma unroll
    for (int rr = 0; rr < 8; ++rr) {
        const int qrow = 8 * wv + rr;
        float* row = Ps + qrow * PSTR;
        const int Cq = (qrow & 7) << 2;
        float v[5];
        #pragma unroll
        for (int j = 0; j < 5; ++j) v[j] = row[(lane + 64 * j) ^ Cq];
        float m = fmaxf(fmaxf(fmaxf(v[0], v[1]), fmaxf(v[2], v[3])), v[4]);
        #pragma unroll
        for (int off = 32; off > 0; off >>= 1) m = fmaxf(m, __shfl_xor(m, off, 64));
        float e[5], sum = 0.f;
        #pragma unroll
        for (int j = 0; j < 5; ++j) { e[j] = __expf(v[j] - m); sum += e[j]; }
        #pragma unroll
        for (int off = 32; off > 0; off >>= 1) sum += __shfl_xor(sum, off, 64);
        const float inv = 1.0f / sum;
        #pragma unroll
        for (int j = 0; j < 5; ++j)
            row[(lane + 64 * j) ^ Cq] = e[j] * inv;      // exact 0 out-of-band (exp(-inf))
    }
    __syncthreads();   // barrier 2: only LDS outstanding -> vmcnt(0) is free

    // ---- attn sweep: fire-and-forget NT stores, drain under PV + kernel tail ----
    const int W0 = (q0 >> 2) - 32;                       // base/4 (may be negative)
    #pragma unroll
    for (int rr = 0; rr < 8; ++rr) {
        const int qrow = 8 * wv + rr;
        const float* row = Ps + qrow * PSTR;
        const int Cq = (qrow & 7) << 2;
        f32x4* arow4 = (f32x4*)(attn_out + ((size_t)bh * S_LEN + q0 + qrow) * S_LEN);
        #pragma unroll
        for (int it = 0; it < 8; ++it) {
            const int s = lane + 64 * it;
            const int d = s - W0;
            f32x4 p4 = {0.f, 0.f, 0.f, 0.f};
            if ((unsigned)d < 80u)
                p4 = *(const f32x4*)(row + ((4 * d) ^ Cq));
            __builtin_nontemporal_store(p4, arow4 + s);
        }
    }

    // ---- PV phase: A from Ps (LDS, swizzled), B straight from global V ----
    f32x4 o0 = {0.f, 0.f, 0.f, 0.f}, o1 = {0.f, 0.f, 0.f, 0.f};
    const float* vcol = Vh + 16 * wv + col;
    const int Cr = (col & 7) << 2;                       // (16qt+col)&7 == col&7
    #pragma unroll
    for (int c = 0; c < NCH; ++c) {
        #pragma unroll
        for (int h = 0; h < 2; ++h) {
            const int k0l = c * 64 + 32 * h + 8 * quad;  // klocal for this frag
            const int k0g = base + k0l;
            f32x4 va, vb;
            #pragma unroll
            for (int j = 0; j < 4; ++j) {
                int kgc = min(max(k0g + j, 0), S_LEN - 1);
                va[j] = vcol[(size_t)kgc * DK];
            }
            #pragma unroll
            for (int j = 0; j < 4; ++j) {
                int kgc = min(max(k0g + 4 + j, 0), S_LEN - 1);
                vb[j] = vcol[(size_t)kgc * DK];
            }
            bf16x8 vf = pack8(va, vb);
            #pragma unroll
            for (int qt = 0; qt < 2; ++qt) {
                const float* prow = Ps + (size_t)(16 * qt + col) * PSTR;
                f32x4 a = *(const f32x4*)(prow + (k0l ^ Cr));
                f32x4 b = *(const f32x4*)(prow + ((k0l + 4) ^ Cr));
                bf16x8 pf = pack8(a, b);
                if (qt == 0) o0 = __builtin_amdgcn_mfma_f32_16x16x32_bf16(pf, vf, o0, 0, 0, 0);
                else         o1 = __builtin_amdgcn_mfma_f32_16x16x32_bf16(pf, vf, o1, 0, 0, 0);
            }
        }
    }

    // ---- ctx write: q = 16qt + quad*4 + r, d = 16wv + col ----
    {
        float* Cg = ctx_out + ((size_t)bh * S_LEN + q0) * DK;
        #pragma unroll
        for (int r = 0; r < 4; ++r) {
            Cg[(size_t)(quad * 4 + r) * DK + 16 * wv + col]      = o0[r];
            Cg[(size_t)(16 + quad * 4 + r) * DK + 16 * wv + col] = o1[r];
        }
    }
}

extern "C" void kernel_launch(void* const* d_in, const int* in_sizes, int n_in,
                              void* d_out, int out_size, void* d_ws, size_t ws_size,
                              hipStream_t stream) {
    const float* Q = (const float*)d_in[0];
    const float* K = (const float*)d_in[1];
    const float* V = (const float*)d_in[2];
    float* out = (float*)d_out;

    const int BH = in_sizes[0] / (S_LEN * DK);          // B*H = 16
    const size_t ctx_elems = (size_t)BH * S_LEN * DK;
    float* ctx  = out;
    float* attn = out + ctx_elems;

    dim3 grid(BH * (S_LEN / TQ));                       // 1024 blocks
    band_attn_v9<<<grid, 256, 0, stream>>>(Q, K, V, ctx, attn);
}

// Round 3
// 297.000 us; speedup vs baseline: 1.0216x; 1.0216x over previous
//
#include <hip/hip_runtime.h>
#include <hip/hip_bf16.h>
#include <math.h>

#define S_LEN 2048
#define DK 64
#define TQ 32          // queries per block
#define KLW 320        // klocal band width
#define NCH 5          // 5 chunks of 64 keys
#define PSTR 320       // Ps row stride (floats); banks via XOR swizzle; 32*320*4B = 40960B -> 4 blocks/CU

typedef __attribute__((ext_vector_type(8))) short bf16x8;
typedef __attribute__((ext_vector_type(4))) float f32x4;

__device__ __forceinline__ bf16x8 pack8(f32x4 a, f32x4 b) {
    union { __hip_bfloat162 h[4]; bf16x8 v; } u;
    u.h[0] = __float22bfloat162_rn(make_float2(a[0], a[1]));
    u.h[1] = __float22bfloat162_rn(make_float2(a[2], a[3]));
    u.h[2] = __float22bfloat162_rn(make_float2(b[0], b[1]));
    u.h[3] = __float22bfloat162_rn(make_float2(b[2], b[3]));
    return u.v;
}

// Swizzle: element kl of row q lives at Ps[q*PSTR + (kl ^ ((q&7)<<2))].
// XOR constant has only bits 2..4 -> 16B granules permute within each 32-float
// block; 4-aligned vector reads stay contiguous ((x^C)+i == (x+i)^C for i<4).

__global__ __launch_bounds__(256, 4) void band_attn_v10(
    const float* __restrict__ Q,
    const float* __restrict__ K,
    const float* __restrict__ V,
    float* __restrict__ ctx_out,   // [BH, S, DK]
    float* __restrict__ attn_out)  // [BH, S, S]
{
    __shared__ __align__(16) float Ps[TQ * PSTR];   // 40960 B -> 4 blocks/CU

    const int tid  = threadIdx.x;

    // XCD-aware swizzle (T1): each XCD owns 128 consecutive logical tiles
    // (= 2 heads, K+V 2.1 MB -> L2-resident band re-reads).
    const int nb = gridDim.x;
    int lb = blockIdx.x;
    if ((nb & 7) == 0) {
        const int per = nb >> 3;
        lb = (blockIdx.x & 7) * per + (blockIdx.x >> 3);
    }
    const int bh   = lb >> 6;                    // 64 tiles per head
    const int q0   = (lb & 63) * TQ;
    const int base = q0 - 128;                   // kg = base + kl; base % 4 == 0

    const int lane = tid & 63;
    const int wv   = tid >> 6;
    const int col  = lane & 15;
    const int quad = lane >> 4;

    const float* Qh = Q + ((size_t)bh * S_LEN + q0) * DK;
    const float* Kh = K + (size_t)bh * S_LEN * DK;
    const float* Vh = V + (size_t)bh * S_LEN * DK;

    // ---- Q A-frags (pre-scaled by 1/8), loaded once ----
    bf16x8 qf[2][2];
    #pragma unroll
    for (int qt = 0; qt < 2; ++qt)
        #pragma unroll
        for (int h = 0; h < 2; ++h) {
            const float* qp = Qh + (size_t)(16 * qt + col) * DK + 32 * h + 8 * quad;
            f32x4 a = *(const f32x4*)qp;
            f32x4 b = *(const f32x4*)(qp + 4);
            a *= 0.125f; b *= 0.125f;
            qf[qt][h] = pack8(a, b);
        }

    // ---- score phase: B-frags straight from global K ----
    #pragma unroll
    for (int c = 0; c < NCH; ++c) {
        const int kl  = c * 64 + 16 * wv + col;          // this lane's key (klocal)
        const int kg  = base + kl;
        const int kgc = min(max(kg, 0), S_LEN - 1);      // clamp; mask fixes OOB
        bf16x8 kf[2];
        #pragma unroll
        for (int h = 0; h < 2; ++h) {
            const float* kp = Kh + (size_t)kgc * DK + 32 * h + 8 * quad;
            kf[h] = pack8(*(const f32x4*)kp, *(const f32x4*)(kp + 4));
        }
        #pragma unroll
        for (int qt = 0; qt < 2; ++qt) {
            f32x4 acc = {0.f, 0.f, 0.f, 0.f};
            acc = __builtin_amdgcn_mfma_f32_16x16x32_bf16(qf[qt][0], kf[0], acc, 0, 0, 0);
            acc = __builtin_amdgcn_mfma_f32_16x16x32_bf16(qf[qt][1], kf[1], acc, 0, 0, 0);
            #pragma unroll
            for (int r = 0; r < 4; ++r) {
                const int qloc = 16 * qt + quad * 4 + r;
                const bool ok = ((unsigned)kg < S_LEN) && (kl > qloc) && (kl <= qloc + 255);
                Ps[qloc * PSTR + (kl ^ ((qloc & 7) << 2))] = ok ? acc[r] : -INFINITY;
            }
        }
    }

    __syncthreads();   // barrier 1: K loads retired long ago -> cheap vmcnt

    // ---- softmax: LDS-only (no global stores before barrier 2) ----
    #pragma unroll
    for (int rr = 0; rr < 8; ++rr) {
        const int qrow = 8 * wv + rr;
        float* row = Ps + qrow * PSTR;
        const int Cq = (qrow & 7) << 2;
        float v[5];
        #pragma unroll
        for (int j = 0; j < 5; ++j) v[j] = row[(lane + 64 * j) ^ Cq];
        float m = fmaxf(fmaxf(fmaxf(v[0], v[1]), fmaxf(v[2], v[3])), v[4]);
        #pragma unroll
        for (int off = 32; off > 0; off >>= 1) m = fmaxf(m, __shfl_xor(m, off, 64));
        float e[5], sum = 0.f;
        #pragma unroll
        for (int j = 0; j < 5; ++j) { e[j] = __expf(v[j] - m); sum += e[j]; }
        #pragma unroll
        for (int off = 32; off > 0; off >>= 1) sum += __shfl_xor(sum, off, 64);
        const float inv = 1.0f / sum;
        #pragma unroll
        for (int j = 0; j < 5; ++j)
            row[(lane + 64 * j) ^ Cq] = e[j] * inv;      // exact 0 out-of-band (exp(-inf))
    }
    __syncthreads();   // barrier 2: only LDS outstanding -> vmcnt(0) is free

    // ---- attn sweep: PLAIN cached f32x4 stores (A/B vs nontemporal) ----
    // 268 MB @ 89% of kernel bytes: if the nt path caps write throughput,
    // cached write-back (the fill's 6.4 TB/s path) is the fix.
    const int W0 = (q0 >> 2) - 32;                       // base/4 (may be negative)
    #pragma unroll
    for (int rr = 0; rr < 8; ++rr) {
        const int qrow = 8 * wv + rr;
        const float* row = Ps + qrow * PSTR;
        const int Cq = (qrow & 7) << 2;
        f32x4* arow4 = (f32x4*)(attn_out + ((size_t)bh * S_LEN + q0 + qrow) * S_LEN);
        #pragma unroll
        for (int it = 0; it < 8; ++it) {
            const int s = lane + 64 * it;
            const int d = s - W0;
            f32x4 p4 = {0.f, 0.f, 0.f, 0.f};
            if ((unsigned)d < 80u)
                p4 = *(const f32x4*)(row + ((4 * d) ^ Cq));
            arow4[s] = p4;
        }
    }

    // ---- PV phase: A from Ps (LDS, swizzled), B straight from global V ----
    f32x4 o0 = {0.f, 0.f, 0.f, 0.f}, o1 = {0.f, 0.f, 0.f, 0.f};
    const float* vcol = Vh + 16 * wv + col;
    const int Cr = (col & 7) << 2;                       // (16qt+col)&7 == col&7
    #pragma unroll
    for (int c = 0; c < NCH; ++c) {
        #pragma unroll
        for (int h = 0; h < 2; ++h) {
            const int k0l = c * 64 + 32 * h + 8 * quad;  // klocal for this frag
            const int k0g = base + k0l;
            f32x4 va, vb;
            #pragma unroll
            for (int j = 0; j < 4; ++j) {
                int kgc = min(max(k0g + j, 0), S_LEN - 1);
                va[j] = vcol[(size_t)kgc * DK];
            }
            #pragma unroll
            for (int j = 0; j < 4; ++j) {
                int kgc = min(max(k0g + 4 + j, 0), S_LEN - 1);
                vb[j] = vcol[(size_t)kgc * DK];
            }
            bf16x8 vf = pack8(va, vb);
            #pragma unroll
            for (int qt = 0; qt < 2; ++qt) {
                const float* prow = Ps + (size_t)(16 * qt + col) * PSTR;
                f32x4 a = *(const f32x4*)(prow + (k0l ^ Cr));
                f32x4 b = *(const f32x4*)(prow + ((k0l + 4) ^ Cr));
                bf16x8 pf = pack8(a, b);
                if (qt == 0) o0 = __builtin_amdgcn_mfma_f32_16x16x32_bf16(pf, vf, o0, 0, 0, 0);
                else         o1 = __builtin_amdgcn_mfma_f32_16x16x32_bf16(pf, vf, o1, 0, 0, 0);
            }
        }
    }

    // ---- ctx write: q = 16qt + quad*4 + r, d = 16wv + col ----
    {
        float* Cg = ctx_out + ((size_t)bh * S_LEN + q0) * DK;
        #pragma unroll
        for (int r = 0; r < 4; ++r) {
            Cg[(size_t)(quad * 4 + r) * DK + 16 * wv + col]      = o0[r];
            Cg[(size_t)(16 + quad * 4 + r) * DK + 16 * wv + col] = o1[r];
        }
    }
}

extern "C" void kernel_launch(void* const* d_in, const int* in_sizes, int n_in,
                              void* d_out, int out_size, void* d_ws, size_t ws_size,
                              hipStream_t stream) {
    const float* Q = (const float*)d_in[0];
    const float* K = (const float*)d_in[1];
    const float* V = (const float*)d_in[2];
    float* out = (float*)d_out;

    const int BH = in_sizes[0] / (S_LEN * DK);          // B*H = 16
    const size_t ctx_elems = (size_t)BH * S_LEN * DK;
    float* ctx  = out;
    float* attn = out + ctx_elems;

    dim3 grid(BH * (S_LEN / TQ));                       // 1024 blocks
    band_attn_v10<<<grid, 256, 0, stream>>>(Q, K, V, ctx, attn);
}